// Round 7
// baseline (164.980 us; speedup 1.0000x reference)
//
#include <hip/hip_runtime.h>

typedef unsigned short u16;
typedef unsigned int   u32;
typedef __attribute__((ext_vector_type(8))) short          shortx8;
typedef __attribute__((ext_vector_type(8))) unsigned short ushortx8;
typedef __attribute__((ext_vector_type(4))) float          floatx4;

#define AS1 __attribute__((address_space(1)))
#define AS3 __attribute__((address_space(3)))

#define SEG 8208   // 8192 + 16 pad cols per batch segment of Vt
#define LV  16416  // 2 * SEG

__device__ __forceinline__ float b2f(u16 v) {
  return __uint_as_float(((u32)v) << 16);
}
__device__ __forceinline__ u16 f2b(float f) {
  u32 u = __float_as_uint(f);
  u += 0x7FFF + ((u >> 16) & 1);   // RNE
  return (u16)(u >> 16);
}
__device__ __forceinline__ void cp16(const void* g, void* l) {
  // 16B/lane global->LDS DMA; LDS dest must be wave-uniform base + lane*16
  __builtin_amdgcn_global_load_lds((AS1 u32*)g, (AS3 u32*)l, 16, 0, 0);
}

// ---------------------------------------------------------------------------
// Fused prep.  Block map (mini-GEMMs FIRST so they run under the casts):
//   [0,16)        Mc  = Wq @ Wk^T  -> BtAll rows    0-511  (=McT)
//   [16,32)       Wvo = Wv @ Wout  -> BtAll rows 512-1023  (=WvoT)
//                 (scores = x Mc x^T replaces Q.K^T; Vw = x Wvo makes the
//                  attention PV output THE final output -- proj deleted)
//   [32,4128)     cast x->bf16 (to guarded xb) + width rows
//   [4128,4192)   Vt pad-column zeroing
__global__ __launch_bounds__(256)
void prep(const float* __restrict__ x, const float* __restrict__ w_width,
          const float* __restrict__ b_width, const float* __restrict__ w_qkv,
          const float* __restrict__ w_out, u16* __restrict__ xb,
          float* __restrict__ width, u16* __restrict__ BtAll,
          u16* __restrict__ Vt) {
  __shared__ alignas(16) u16 shb[17408];   // mini-GEMM staging / epilogue
  const int b = blockIdx.x;
  if (b < 32) {                      // ---- Mc / Wvo mini-GEMM (128x128 tile)
    const bool isMc = (b < 16);
    const int t    = isMc ? b : b - 16;
    const int row0 = (t >> 2) * 128;       // A-row (i) block
    const int col0 = (t & 3) * 128;        // out-col (j) block
    const int tid  = threadIdx.x;
    const int lane = tid & 63;
    const int wave = tid >> 6;
    const int quad = lane >> 4;
    const int lr   = lane & 15;
    const int wr   = (wave >> 1) * 64;
    const int wc   = (wave & 1) * 64;
    u16* As = shb;
    u16* Bs = shb + 8192;

    floatx4 acc[4][4];
#pragma unroll
    for (int i = 0; i < 4; ++i)
#pragma unroll
      for (int j = 0; j < 4; ++j) acc[i][j] = (floatx4)0.0f;

    int srow[4], scol[4];
#pragma unroll
    for (int p = 0; p < 4; ++p) {
      int c = p * 256 + tid;
      srow[p] = c >> 3;
      scol[p] = ((c & 7) ^ (srow[p] & 7)) * 8;
    }
    const int swz = lr & 7;

    for (int k0 = 0; k0 < 512; k0 += 64) {
      // A: Mc -> Wq rows; Wvo -> Wv rows (w_qkv cols 1024+k)
#pragma unroll
      for (int p = 0; p < 4; ++p) {
        const float* ga = w_qkv + (size_t)(row0 + srow[p]) * 1536 +
                          (isMc ? 0 : 1024) + k0 + scol[p];
        floatx4 a0 = *(const floatx4*)ga;
        floatx4 a1 = *(const floatx4*)(ga + 4);
        ushortx8 o;
#pragma unroll
        for (int j = 0; j < 4; ++j) { o[j] = f2b(a0[j]); o[4 + j] = f2b(a1[j]); }
        *(ushortx8*)&As[(p * 256 + tid) * 8] = o;
      }
      // B: Mc -> Wk rows (w_qkv cols 512+k); Wvo -> Wout^T rows (strided)
#pragma unroll
      for (int p = 0; p < 4; ++p) {
        ushortx8 o;
        if (isMc) {
          const float* gb = w_qkv + (size_t)(col0 + srow[p]) * 1536 + 512 +
                            k0 + scol[p];
          floatx4 b0 = *(const floatx4*)gb;
          floatx4 b1 = *(const floatx4*)(gb + 4);
#pragma unroll
          for (int j = 0; j < 4; ++j) { o[j] = f2b(b0[j]); o[4 + j] = f2b(b1[j]); }
        } else {
          // B[j][k] = w_out[k][j], k = k0+scol[p]+0..7, j = col0+srow[p]
          const float* gb = w_out + (size_t)(k0 + scol[p]) * 512 + col0 + srow[p];
#pragma unroll
          for (int j = 0; j < 8; ++j) o[j] = f2b(gb[(size_t)j * 512]);
        }
        *(ushortx8*)&Bs[(p * 256 + tid) * 8] = o;
      }
      __syncthreads();
#pragma unroll
      for (int ks = 0; ks < 2; ++ks) {
        shortx8 af[4], bf[4];
#pragma unroll
        for (int mi = 0; mi < 4; ++mi)
          af[mi] = *(const shortx8*)
              &As[((wr + mi * 16 + lr) * 8 + ((ks * 4 + quad) ^ swz)) * 8];
#pragma unroll
        for (int ni = 0; ni < 4; ++ni)
          bf[ni] = *(const shortx8*)
              &Bs[((wc + ni * 16 + lr) * 8 + ((ks * 4 + quad) ^ swz)) * 8];
#pragma unroll
        for (int mi = 0; mi < 4; ++mi)
#pragma unroll
          for (int ni = 0; ni < 4; ++ni)
            acc[mi][ni] = __builtin_amdgcn_mfma_f32_16x16x32_bf16(
                af[mi], bf[ni], acc[mi][ni], 0, 0, 0);
      }
      __syncthreads();
    }
    // transposed epilogue: BtAll[(Wvo? +512) + col0+j][row0+i]
    u16* outp = BtAll + (isMc ? 0 : (size_t)512 * 512);
#pragma unroll
    for (int mi = 0; mi < 4; ++mi)
#pragma unroll
      for (int ni = 0; ni < 4; ++ni)
#pragma unroll
        for (int r = 0; r < 4; ++r)
          shb[(wc + ni * 16 + lr) * 136 + wr + mi * 16 + quad * 4 + r] =
              f2b(acc[mi][ni][r]);
    __syncthreads();
    const int rr = tid >> 4, cc = (tid & 15) * 8;
#pragma unroll
    for (int it = 0; it < 8; ++it) {
      int chl = it * 16 + rr;
      *(ushortx8*)(outp + (size_t)(col0 + chl) * 512 + row0 + cc) =
          *(const ushortx8*)&shb[chl * 136 + cc];
    }
  } else if (b < 4128) {             // ---- cast x -> bf16, compute width
    const int lane = threadIdx.x & 63;
    const int row  = (b - 32) * 4 + (threadIdx.x >> 6);
    const float* xp = x + (size_t)row * 512 + lane * 8;
    floatx4 v0 = *(const floatx4*)xp;
    floatx4 v1 = *(const floatx4*)(xp + 4);
    floatx4 w0 = *(const floatx4*)(w_width + lane * 8);
    floatx4 w1 = *(const floatx4*)(w_width + lane * 8 + 4);
    float s = 0.f;
    ushortx8 o;
#pragma unroll
    for (int j = 0; j < 4; ++j) {
      s += v0[j] * w0[j] + v1[j] * w1[j];
      o[j] = f2b(v0[j]); o[4 + j] = f2b(v1[j]);
    }
    *(ushortx8*)(xb + (size_t)row * 512 + lane * 8) = o;
#pragma unroll
    for (int m = 32; m >= 1; m >>= 1) s += __shfl_xor(s, m, 64);
    if (lane == 0)
      width[row] = 16.f / (1.f + __expf(-(s + b_width[0]))) + 1.f;
  } else {                           // ---- Vt pad-column zeroing
    const int idx = (b - 4128) * 256 + threadIdx.x;  // 512 ch * 32 pad cols
    const int ch = idx >> 5;
    const int k  = idx & 31;
    const int seg = k >> 4;
    const int j   = k & 15;
    const int col = seg * SEG + (j < 8 ? j : 8192 + j);
    Vt[(size_t)ch * LV + col] = 0;
  }
}

// ---------------------------------------------------------------------------
// C = A[M][512] @ Bt[N][512]^T, bf16 in, fp32 acc.  128x128 tile, BK=64,
// XOR-swizzled LDS staging, LDS-shuffled coalesced epilogues.  N=1024:
// cols [0,512) -> Qm rows (Qb); cols [512,1024) -> Vw, transposed scatter
// into batch-padded Vt (Vw = x @ (Wv Wout): PV output is the FINAL output).
__global__ __launch_bounds__(256, 3)
void gemm_qv(const u16* __restrict__ A, const u16* __restrict__ Bt,
             u16* __restrict__ Qb, u16* __restrict__ Vt) {
  const int K = 512;
  __shared__ alignas(16) u16 lds[17408];        // 34,816 B (union)
  u16* As = lds;                                // 8192 u16 (128 x 64)
  u16* Bs = lds + 8192;                         // 8192 u16
  const int tid  = threadIdx.x;
  const int lane = tid & 63;
  const int wave = tid >> 6;
  const int quad = lane >> 4;
  const int lr   = lane & 15;
  const int row0 = blockIdx.x * 128;
  const int col0 = blockIdx.y * 128;
  const int wr   = (wave >> 1) * 64;
  const int wc   = (wave & 1) * 64;

  floatx4 acc[4][4];
#pragma unroll
  for (int i = 0; i < 4; ++i)
#pragma unroll
    for (int j = 0; j < 4; ++j) acc[i][j] = (floatx4)0.0f;

  // chunk c = p*256+tid -> LDS slot c; row c>>3, phys colblk (c&7)^(row&7)
  int srow[4], scol[4];
#pragma unroll
  for (int p = 0; p < 4; ++p) {
    int c = p * 256 + tid;
    srow[p] = c >> 3;
    scol[p] = ((c & 7) ^ (srow[p] & 7)) * 8;
  }
  const int swz = lr & 7;

  for (int k0 = 0; k0 < K; k0 += 64) {
#pragma unroll
    for (int p = 0; p < 4; ++p)
      cp16(A + (size_t)(row0 + srow[p]) * K + k0 + scol[p], &As[(p * 256 + tid) * 8]);
#pragma unroll
    for (int p = 0; p < 4; ++p)
      cp16(Bt + (size_t)(col0 + srow[p]) * K + k0 + scol[p], &Bs[(p * 256 + tid) * 8]);
    __syncthreads();

#pragma unroll
    for (int ks = 0; ks < 2; ++ks) {
      shortx8 af[4], bf[4];
#pragma unroll
      for (int mi = 0; mi < 4; ++mi)
        af[mi] = *(const shortx8*)
            &As[((wr + mi * 16 + lr) * 8 + ((ks * 4 + quad) ^ swz)) * 8];
#pragma unroll
      for (int ni = 0; ni < 4; ++ni)
        bf[ni] = *(const shortx8*)
            &Bs[((wc + ni * 16 + lr) * 8 + ((ks * 4 + quad) ^ swz)) * 8];
#pragma unroll
      for (int mi = 0; mi < 4; ++mi)
#pragma unroll
        for (int ni = 0; ni < 4; ++ni)
          acc[mi][ni] = __builtin_amdgcn_mfma_f32_16x16x32_bf16(
              af[mi], bf[ni], acc[mi][ni], 0, 0, 0);
    }
    __syncthreads();
  }

  // C/D layout: col = lane&15, row = quad*4 + reg  [verified m89/m91]
  if (col0 < 512) {                  // ---- Qm: row-major LDS, coalesced out
    const int cb = col0;
#pragma unroll
    for (int mi = 0; mi < 4; ++mi)
#pragma unroll
      for (int ni = 0; ni < 4; ++ni)
#pragma unroll
        for (int r = 0; r < 4; ++r)
          lds[(wr + mi * 16 + quad * 4 + r) * 136 + wc + ni * 16 + lr] =
              f2b(acc[mi][ni][r]);
    __syncthreads();
    const int rr = tid >> 4, cc = (tid & 15) * 8;
#pragma unroll
    for (int it = 0; it < 8; ++it) {
      int row = it * 16 + rr;
      *(ushortx8*)(Qb + (size_t)(row0 + row) * 512 + cb + cc) =
          *(const ushortx8*)&lds[row * 136 + cc];
    }
  } else {                           // ---- Vw: transposed LDS, coalesced out
    const int cb = col0 - 512;
    const int bb = row0 >> 13, pib0 = row0 & 8191;
#pragma unroll
    for (int mi = 0; mi < 4; ++mi)
#pragma unroll
      for (int ni = 0; ni < 4; ++ni)
#pragma unroll
        for (int r = 0; r < 4; ++r)
          lds[(wc + ni * 16 + lr) * 136 + wr + mi * 16 + quad * 4 + r] =
              f2b(acc[mi][ni][r]);
    __syncthreads();
    const int rr = tid >> 4, cc = (tid & 15) * 8;
#pragma unroll
    for (int it = 0; it < 8; ++it) {
      int chl = it * 16 + rr;
      ushortx8 v = *(const ushortx8*)&lds[chl * 136 + cc];
      *(ushortx8*)(Vt + (size_t)(cb + chl) * LV + (size_t)bb * SEG + 8 + pib0 + cc) = v;
    }
  }
}

// ---------------------------------------------------------------------------
// Fused local attention, v5: PV output IS the final output (Vw = x WvWout),
// so there is no projection phase, no Osw round-trip, and NO barriers --
// each wave owns 16 rows end-to-end: QK^T (Qm.x), in-reg softmax, PV -> fp32
// stores.  "+v Wout" residual = Vw[self], folded via P's +1 self slot.
__global__ __launch_bounds__(256, 1)
void attn_fused(const u16* __restrict__ Q, const u16* __restrict__ Kx,
                const u16* __restrict__ Vt, const float* __restrict__ width,
                float* __restrict__ Out) {
  __shared__ alignas(16) u16 P[4][16][32];    // 4KB: per-wave P (A-layout)
  const int tid  = threadIdx.x;
  const int lane = tid & 63;
  const int wave = tid >> 6;
  const int quad = lane >> 4;
  const int lr   = lane & 15;
  const int p0   = blockIdx.x * 64;
  const int pw   = p0 + wave * 16;
  const int pibw = pw & 8191;
  const int bb   = pw >> 13;
  const size_t cb0 = (size_t)bb * SEG + pibw;   // Vt col of window slot 0

  // ---- hoisted Vw half-0 loads (independent of all other phases)
  shortx8 vfA[16];
#pragma unroll
  for (int ctl = 0; ctl < 16; ++ctl)
    vfA[ctl] = *(const shortx8*)(Vt + (size_t)(ctl * 16 + lr) * LV +
                                 cb0 + quad * 8);

  // ---- Phase A: scores 16x32 over all 512 channels (this wave's rows)
  floatx4 s0 = (floatx4)0.0f, s1 = (floatx4)0.0f;
#pragma unroll 4
  for (int s = 0; s < 16; ++s) {
    const int k0 = s * 32 + quad * 8;
    shortx8 af = *(const shortx8*)(Q  + (size_t)(pw + lr) * 512 + k0);
    shortx8 f0 = *(const shortx8*)(Kx + (ptrdiff_t)(pw - 8 + lr) * 512 + k0);
    shortx8 f1 = *(const shortx8*)(Kx + (ptrdiff_t)(pw + 8 + lr) * 512 + k0);
    s0 = __builtin_amdgcn_mfma_f32_16x16x32_bf16(af, f0, s0, 0, 0, 0);
    s1 = __builtin_amdgcn_mfma_f32_16x16x32_bf16(af, f1, s1, 0, 0, 0);
  }

  // ---- issue Vw half-1 loads; they land during softmax / PV(h0)
  shortx8 vfB[16];
#pragma unroll
  for (int ctl = 0; ctl < 16; ++ctl)
    vfB[ctl] = *(const shortx8*)(Vt + (size_t)(256 + ctl * 16 + lr) * LV +
                                 cb0 + quad * 8);

  // ---- Softmax in-register.  Thread holds rows quad*4+r, cols {lr, lr+16}.
  {
    const float scale = 0.044194173824159216f;   // 512^-0.5
    floatx4 wv = *(const floatx4*)(width + pw + quad * 4);
#pragma unroll
    for (int r = 0; r < 4; ++r) {
      const int row = quad * 4 + r;
      const int d0  = lr - row;            // window slot of col lr
      const int d1  = d0 + 16;             // window slot of col lr+16
      const int jb0 = pibw + lr - 8;       // k position within batch
      const int jb1 = jb0 + 16;
      float rel0 = fabsf((float)(d0 - 8));
      float rel1 = fabsf((float)(d1 - 8));
      float mk0 = 1.f / (1.f + __expf(-5.f * (wv[r] - rel0)));
      float mk1 = 1.f / (1.f + __expf(-5.f * (wv[r] - rel1)));
      float val0 = (d0 >= 0)
          ? (((unsigned)jb0 < 8192u ? s0[r] * scale : 0.f) - (1.f - mk0) * 10000.f)
          : -1e30f;
      float val1 = (d1 <= 16)
          ? (((unsigned)jb1 < 8192u ? s1[r] * scale : 0.f) - (1.f - mk1) * 10000.f)
          : -1e30f;
      float mx = fmaxf(val0, val1);
#pragma unroll
      for (int m = 8; m >= 1; m >>= 1) mx = fmaxf(mx, __shfl_xor(mx, m, 64));
      float e0 = __expf(val0 - mx), e1 = __expf(val1 - mx);
      float sum = e0 + e1;
#pragma unroll
      for (int m = 8; m >= 1; m >>= 1) sum += __shfl_xor(sum, m, 64);
      const float inv = 1.f / sum;
      // +1 at the self slot (d==8) folds the "+ v Wout" into PV
      P[wave][row][lr]      = f2b(e0 * inv + (d0 == 8 ? 1.f : 0.f));
      P[wave][row][lr + 16] = f2b(e1 * inv + (d1 == 8 ? 1.f : 0.f));
    }
  }
  // P write->read is same-wave: DS ops are in-order per wave, no barrier.
  shortx8 pf = *(const shortx8*)&P[wave][lr][quad * 8];  // A[m=lr][k=quad*8+j]

  // ---- PV: out frag (row=pos quad*4+r, col=channel lr) -> direct fp32 store
#pragma unroll
  for (int ctl = 0; ctl < 16; ++ctl) {
    floatx4 o = __builtin_amdgcn_mfma_f32_16x16x32_bf16(pf, vfA[ctl],
                                                        (floatx4)0.0f, 0, 0, 0);
#pragma unroll
    for (int r = 0; r < 4; ++r)
      Out[(size_t)(pw + quad * 4 + r) * 512 + ctl * 16 + lr] = o[r];
  }
#pragma unroll
  for (int ctl = 0; ctl < 16; ++ctl) {
    floatx4 o = __builtin_amdgcn_mfma_f32_16x16x32_bf16(pf, vfB[ctl],
                                                        (floatx4)0.0f, 0, 0, 0);
#pragma unroll
    for (int r = 0; r < 4; ++r)
      Out[(size_t)(pw + quad * 4 + r) * 512 + 256 + ctl * 16 + lr] = o[r];
  }
}

// ---------------------------------------------------------------------------
extern "C" void kernel_launch(void* const* d_in, const int* in_sizes, int n_in,
                              void* d_out, int out_size, void* d_ws, size_t ws_size,
                              hipStream_t stream) {
  const float* x       = (const float*)d_in[0];  // [2,8192,512] fp32
  const float* w_qkv   = (const float*)d_in[1];  // [512,1536]  fp32
  const float* w_width = (const float*)d_in[2];  // [512,1]     fp32
  const float* b_width = (const float*)d_in[3];  // [1]         fp32
  const float* w_out   = (const float*)d_in[4];  // [512,512]   fp32
  float* out = (float*)d_out;                    // [2,8192,512] fp32

  const int M = 16384;
  char* ws = (char*)d_ws;
  // HBM-channel stagger (R6 win): consecutive large buffers offset by an
  // extra 8KB so no two hot read streams (Qm / xb / Vt) are 16MB-aligned.
  // [0,8192)           guard page (below-batch K-window reads land here)
  u16*   xb    = (u16*)(ws + 8192);                // 16,777,216
  u16*   Qb    = (u16*)(ws + 16793600);            // 16,777,216 (Qm)
  u16*   Vt    = (u16*)(ws + 33579008);            // 512*16416*2 = 16,809,984
  u16*   BtAll = (u16*)(ws + 50397184);            // McT | WvoT = 1,048,576
  float* width = (float*)(ws + 51445760);          //     65,536

  prep<<<dim3(4192), dim3(256), 0, stream>>>(x, w_width, b_width, w_qkv, w_out,
                                             xb, width, BtAll, Vt);
  gemm_qv<<<dim3(M / 128, 8), dim3(256), 0, stream>>>(xb, BtAll, Qb, Vt);
  attn_fused<<<dim3(M / 64), dim3(256), 0, stream>>>(Qb, xb, Vt, width, out);
}

// Round 8
// 148.399 us; speedup vs baseline: 1.1117x; 1.1117x over previous
//
#include <hip/hip_runtime.h>

typedef unsigned short u16;
typedef unsigned int   u32;
typedef __attribute__((ext_vector_type(8))) short          shortx8;
typedef __attribute__((ext_vector_type(8))) unsigned short ushortx8;
typedef __attribute__((ext_vector_type(4))) float          floatx4;

#define AS1 __attribute__((address_space(1)))
#define AS3 __attribute__((address_space(3)))

#define SEG 8208   // 8192 + 16 pad cols per batch segment of Vt
#define LV  16416  // 2 * SEG

__device__ __forceinline__ float b2f(u16 v) {
  return __uint_as_float(((u32)v) << 16);
}
__device__ __forceinline__ u16 f2b(float f) {
  u32 u = __float_as_uint(f);
  u += 0x7FFF + ((u >> 16) & 1);   // RNE
  return (u16)(u >> 16);
}
__device__ __forceinline__ void cp16(const void* g, void* l) {
  // 16B/lane global->LDS DMA; LDS dest must be wave-uniform base + lane*16
  __builtin_amdgcn_global_load_lds((AS1 u32*)g, (AS3 u32*)l, 16, 0, 0);
}

// ---------------------------------------------------------------------------
// prep0: w_out (fp32, row-major [k][j]) -> woutT (bf16, [j][k]).  Runs before
// prep on the same stream, so prep's Wvo mini-GEMM can read B coalesced.
// (R7 read w_out transposed with scalar 2KB-stride loads inside the GEMM ->
// prep 60us, MfmaUtil 0.3%.  1MB of traffic belongs in a 3us transpose.)
__global__ __launch_bounds__(256)
void prep0(const float* __restrict__ w_out, u16* __restrict__ woutT) {
  __shared__ u16 tile[32][33];
  const int t  = blockIdx.x;          // 256 = 16x16 tiles of 32x32
  const int cb = (t & 15) * 32;       // j block
  const int rb = (t >> 4) * 32;       // k block
  const int tx = threadIdx.x & 31;
  const int ty = threadIdx.x >> 5;
#pragma unroll
  for (int i = 0; i < 32; i += 8)
    tile[ty + i][tx] = f2b(w_out[(size_t)(rb + ty + i) * 512 + cb + tx]);
  __syncthreads();
#pragma unroll
  for (int i = 0; i < 32; i += 8)
    woutT[(size_t)(cb + ty + i) * 512 + rb + tx] = tile[tx][ty + i];
}

// ---------------------------------------------------------------------------
// Fused prep.  Block map (mini-GEMMs FIRST so they run under the casts):
//   [0,16)        Mc  = Wq @ Wk^T  -> BtAll rows    0-511  (=McT)
//   [16,32)       Wvo = Wv @ Wout  -> BtAll rows 512-1023  (=WvoT)
//                 (scores = x Mc x^T replaces Q.K^T; Vw = x Wvo makes the
//                  attention PV output THE final output -- proj deleted)
//   [32,4128)     cast x->bf16 (to guarded xb) + width rows
//   [4128,4192)   Vt pad-column zeroing
__global__ __launch_bounds__(256)
void prep(const float* __restrict__ x, const float* __restrict__ w_width,
          const float* __restrict__ b_width, const float* __restrict__ w_qkv,
          const u16* __restrict__ woutT, u16* __restrict__ xb,
          float* __restrict__ width, u16* __restrict__ BtAll,
          u16* __restrict__ Vt) {
  __shared__ alignas(16) u16 shb[17408];   // mini-GEMM staging / epilogue
  const int b = blockIdx.x;
  if (b < 32) {                      // ---- Mc / Wvo mini-GEMM (128x128 tile)
    const bool isMc = (b < 16);
    const int t    = isMc ? b : b - 16;
    const int row0 = (t >> 2) * 128;       // A-row (i) block
    const int col0 = (t & 3) * 128;        // out-col (j) block
    const int tid  = threadIdx.x;
    const int lane = tid & 63;
    const int wave = tid >> 6;
    const int quad = lane >> 4;
    const int lr   = lane & 15;
    const int wr   = (wave >> 1) * 64;
    const int wc   = (wave & 1) * 64;
    u16* As = shb;
    u16* Bs = shb + 8192;

    floatx4 acc[4][4];
#pragma unroll
    for (int i = 0; i < 4; ++i)
#pragma unroll
      for (int j = 0; j < 4; ++j) acc[i][j] = (floatx4)0.0f;

    int srow[4], scol[4];
#pragma unroll
    for (int p = 0; p < 4; ++p) {
      int c = p * 256 + tid;
      srow[p] = c >> 3;
      scol[p] = ((c & 7) ^ (srow[p] & 7)) * 8;
    }
    const int swz = lr & 7;

    for (int k0 = 0; k0 < 512; k0 += 64) {
      // A: Mc -> Wq rows; Wvo -> Wv rows (w_qkv cols 1024+k).  Coalesced.
#pragma unroll
      for (int p = 0; p < 4; ++p) {
        const float* ga = w_qkv + (size_t)(row0 + srow[p]) * 1536 +
                          (isMc ? 0 : 1024) + k0 + scol[p];
        floatx4 a0 = *(const floatx4*)ga;
        floatx4 a1 = *(const floatx4*)(ga + 4);
        ushortx8 o;
#pragma unroll
        for (int j = 0; j < 4; ++j) { o[j] = f2b(a0[j]); o[4 + j] = f2b(a1[j]); }
        *(ushortx8*)&As[(p * 256 + tid) * 8] = o;
      }
      // B: Mc -> Wk rows (w_qkv cols 512+k, fp32); Wvo -> woutT rows (bf16).
      // Both coalesced along k.
#pragma unroll
      for (int p = 0; p < 4; ++p) {
        ushortx8 o;
        if (isMc) {
          const float* gb = w_qkv + (size_t)(col0 + srow[p]) * 1536 + 512 +
                            k0 + scol[p];
          floatx4 b0 = *(const floatx4*)gb;
          floatx4 b1 = *(const floatx4*)(gb + 4);
#pragma unroll
          for (int j = 0; j < 4; ++j) { o[j] = f2b(b0[j]); o[4 + j] = f2b(b1[j]); }
        } else {
          o = *(const ushortx8*)(woutT + (size_t)(col0 + srow[p]) * 512 +
                                 k0 + scol[p]);
        }
        *(ushortx8*)&Bs[(p * 256 + tid) * 8] = o;
      }
      __syncthreads();
#pragma unroll
      for (int ks = 0; ks < 2; ++ks) {
        shortx8 af[4], bf[4];
#pragma unroll
        for (int mi = 0; mi < 4; ++mi)
          af[mi] = *(const shortx8*)
              &As[((wr + mi * 16 + lr) * 8 + ((ks * 4 + quad) ^ swz)) * 8];
#pragma unroll
        for (int ni = 0; ni < 4; ++ni)
          bf[ni] = *(const shortx8*)
              &Bs[((wc + ni * 16 + lr) * 8 + ((ks * 4 + quad) ^ swz)) * 8];
#pragma unroll
        for (int mi = 0; mi < 4; ++mi)
#pragma unroll
          for (int ni = 0; ni < 4; ++ni)
            acc[mi][ni] = __builtin_amdgcn_mfma_f32_16x16x32_bf16(
                af[mi], bf[ni], acc[mi][ni], 0, 0, 0);
      }
      __syncthreads();
    }
    // transposed epilogue: BtAll[(Wvo? +512) + col0+j][row0+i]
    u16* outp = BtAll + (isMc ? 0 : (size_t)512 * 512);
#pragma unroll
    for (int mi = 0; mi < 4; ++mi)
#pragma unroll
      for (int ni = 0; ni < 4; ++ni)
#pragma unroll
        for (int r = 0; r < 4; ++r)
          shb[(wc + ni * 16 + lr) * 136 + wr + mi * 16 + quad * 4 + r] =
              f2b(acc[mi][ni][r]);
    __syncthreads();
    const int rr = tid >> 4, cc = (tid & 15) * 8;
#pragma unroll
    for (int it = 0; it < 8; ++it) {
      int chl = it * 16 + rr;
      *(ushortx8*)(outp + (size_t)(col0 + chl) * 512 + row0 + cc) =
          *(const ushortx8*)&shb[chl * 136 + cc];
    }
  } else if (b < 4128) {             // ---- cast x -> bf16, compute width
    const int lane = threadIdx.x & 63;
    const int row  = (b - 32) * 4 + (threadIdx.x >> 6);
    const float* xp = x + (size_t)row * 512 + lane * 8;
    floatx4 v0 = *(const floatx4*)xp;
    floatx4 v1 = *(const floatx4*)(xp + 4);
    floatx4 w0 = *(const floatx4*)(w_width + lane * 8);
    floatx4 w1 = *(const floatx4*)(w_width + lane * 8 + 4);
    float s = 0.f;
    ushortx8 o;
#pragma unroll
    for (int j = 0; j < 4; ++j) {
      s += v0[j] * w0[j] + v1[j] * w1[j];
      o[j] = f2b(v0[j]); o[4 + j] = f2b(v1[j]);
    }
    *(ushortx8*)(xb + (size_t)row * 512 + lane * 8) = o;
#pragma unroll
    for (int m = 32; m >= 1; m >>= 1) s += __shfl_xor(s, m, 64);
    if (lane == 0)
      width[row] = 16.f / (1.f + __expf(-(s + b_width[0]))) + 1.f;
  } else {                           // ---- Vt pad-column zeroing
    const int idx = (b - 4128) * 256 + threadIdx.x;  // 512 ch * 32 pad cols
    const int ch = idx >> 5;
    const int k  = idx & 31;
    const int seg = k >> 4;
    const int j   = k & 15;
    const int col = seg * SEG + (j < 8 ? j : 8192 + j);
    Vt[(size_t)ch * LV + col] = 0;
  }
}

// ---------------------------------------------------------------------------
// C = A[M][512] @ Bt[N][512]^T, bf16 in, fp32 acc.  128x128 tile, BK=64,
// XOR-swizzled LDS staging, LDS-shuffled coalesced epilogues.  N=1024:
// cols [0,512) -> Qm rows (Qb); cols [512,1024) -> Vw, transposed scatter
// into batch-padded Vt (Vw = x @ (Wv Wout): PV output is the FINAL output).
__global__ __launch_bounds__(256, 3)
void gemm_qv(const u16* __restrict__ A, const u16* __restrict__ Bt,
             u16* __restrict__ Qb, u16* __restrict__ Vt) {
  const int K = 512;
  __shared__ alignas(16) u16 lds[17408];        // 34,816 B (union)
  u16* As = lds;                                // 8192 u16 (128 x 64)
  u16* Bs = lds + 8192;                         // 8192 u16
  const int tid  = threadIdx.x;
  const int lane = tid & 63;
  const int wave = tid >> 6;
  const int quad = lane >> 4;
  const int lr   = lane & 15;
  const int row0 = blockIdx.x * 128;
  const int col0 = blockIdx.y * 128;
  const int wr   = (wave >> 1) * 64;
  const int wc   = (wave & 1) * 64;

  floatx4 acc[4][4];
#pragma unroll
  for (int i = 0; i < 4; ++i)
#pragma unroll
    for (int j = 0; j < 4; ++j) acc[i][j] = (floatx4)0.0f;

  // chunk c = p*256+tid -> LDS slot c; row c>>3, phys colblk (c&7)^(row&7)
  int srow[4], scol[4];
#pragma unroll
  for (int p = 0; p < 4; ++p) {
    int c = p * 256 + tid;
    srow[p] = c >> 3;
    scol[p] = ((c & 7) ^ (srow[p] & 7)) * 8;
  }
  const int swz = lr & 7;

  for (int k0 = 0; k0 < K; k0 += 64) {
#pragma unroll
    for (int p = 0; p < 4; ++p)
      cp16(A + (size_t)(row0 + srow[p]) * K + k0 + scol[p], &As[(p * 256 + tid) * 8]);
#pragma unroll
    for (int p = 0; p < 4; ++p)
      cp16(Bt + (size_t)(col0 + srow[p]) * K + k0 + scol[p], &Bs[(p * 256 + tid) * 8]);
    __syncthreads();

#pragma unroll
    for (int ks = 0; ks < 2; ++ks) {
      shortx8 af[4], bf[4];
#pragma unroll
      for (int mi = 0; mi < 4; ++mi)
        af[mi] = *(const shortx8*)
            &As[((wr + mi * 16 + lr) * 8 + ((ks * 4 + quad) ^ swz)) * 8];
#pragma unroll
      for (int ni = 0; ni < 4; ++ni)
        bf[ni] = *(const shortx8*)
            &Bs[((wc + ni * 16 + lr) * 8 + ((ks * 4 + quad) ^ swz)) * 8];
#pragma unroll
      for (int mi = 0; mi < 4; ++mi)
#pragma unroll
        for (int ni = 0; ni < 4; ++ni)
          acc[mi][ni] = __builtin_amdgcn_mfma_f32_16x16x32_bf16(
              af[mi], bf[ni], acc[mi][ni], 0, 0, 0);
    }
    __syncthreads();
  }

  // C/D layout: col = lane&15, row = quad*4 + reg  [verified m89/m91]
  if (col0 < 512) {                  // ---- Qm: row-major LDS, coalesced out
    const int cb = col0;
#pragma unroll
    for (int mi = 0; mi < 4; ++mi)
#pragma unroll
      for (int ni = 0; ni < 4; ++ni)
#pragma unroll
        for (int r = 0; r < 4; ++r)
          lds[(wr + mi * 16 + quad * 4 + r) * 136 + wc + ni * 16 + lr] =
              f2b(acc[mi][ni][r]);
    __syncthreads();
    const int rr = tid >> 4, cc = (tid & 15) * 8;
#pragma unroll
    for (int it = 0; it < 8; ++it) {
      int row = it * 16 + rr;
      *(ushortx8*)(Qb + (size_t)(row0 + row) * 512 + cb + cc) =
          *(const ushortx8*)&lds[row * 136 + cc];
    }
  } else {                           // ---- Vw: transposed LDS, coalesced out
    const int cb = col0 - 512;
    const int bb = row0 >> 13, pib0 = row0 & 8191;
#pragma unroll
    for (int mi = 0; mi < 4; ++mi)
#pragma unroll
      for (int ni = 0; ni < 4; ++ni)
#pragma unroll
        for (int r = 0; r < 4; ++r)
          lds[(wc + ni * 16 + lr) * 136 + wr + mi * 16 + quad * 4 + r] =
              f2b(acc[mi][ni][r]);
    __syncthreads();
    const int rr = tid >> 4, cc = (tid & 15) * 8;
#pragma unroll
    for (int it = 0; it < 8; ++it) {
      int chl = it * 16 + rr;
      ushortx8 v = *(const ushortx8*)&lds[chl * 136 + cc];
      *(ushortx8*)(Vt + (size_t)(cb + chl) * LV + (size_t)bb * SEG + 8 + pib0 + cc) = v;
    }
  }
}

// ---------------------------------------------------------------------------
// Fused local attention, v5: PV output IS the final output (Vw = x WvWout),
// so there is no projection phase, no Osw round-trip, and NO barriers --
// each wave owns 16 rows end-to-end: QK^T (Qm.x), in-reg softmax, PV -> fp32
// stores.  "+v Wout" residual = Vw[self], folded via P's +1 self slot.
__global__ __launch_bounds__(256, 1)
void attn_fused(const u16* __restrict__ Q, const u16* __restrict__ Kx,
                const u16* __restrict__ Vt, const float* __restrict__ width,
                float* __restrict__ Out) {
  __shared__ alignas(16) u16 P[4][16][32];    // 4KB: per-wave P (A-layout)
  const int tid  = threadIdx.x;
  const int lane = tid & 63;
  const int wave = tid >> 6;
  const int quad = lane >> 4;
  const int lr   = lane & 15;
  const int p0   = blockIdx.x * 64;
  const int pw   = p0 + wave * 16;
  const int pibw = pw & 8191;
  const int bb   = pw >> 13;
  const size_t cb0 = (size_t)bb * SEG + pibw;   // Vt col of window slot 0

  // ---- hoisted Vw half-0 loads (independent of all other phases)
  shortx8 vfA[16];
#pragma unroll
  for (int ctl = 0; ctl < 16; ++ctl)
    vfA[ctl] = *(const shortx8*)(Vt + (size_t)(ctl * 16 + lr) * LV +
                                 cb0 + quad * 8);

  // ---- Phase A: scores 16x32 over all 512 channels (this wave's rows)
  floatx4 s0 = (floatx4)0.0f, s1 = (floatx4)0.0f;
#pragma unroll 4
  for (int s = 0; s < 16; ++s) {
    const int k0 = s * 32 + quad * 8;
    shortx8 af = *(const shortx8*)(Q  + (size_t)(pw + lr) * 512 + k0);
    shortx8 f0 = *(const shortx8*)(Kx + (ptrdiff_t)(pw - 8 + lr) * 512 + k0);
    shortx8 f1 = *(const shortx8*)(Kx + (ptrdiff_t)(pw + 8 + lr) * 512 + k0);
    s0 = __builtin_amdgcn_mfma_f32_16x16x32_bf16(af, f0, s0, 0, 0, 0);
    s1 = __builtin_amdgcn_mfma_f32_16x16x32_bf16(af, f1, s1, 0, 0, 0);
  }

  // ---- issue Vw half-1 loads; they land during softmax / PV(h0)
  shortx8 vfB[16];
#pragma unroll
  for (int ctl = 0; ctl < 16; ++ctl)
    vfB[ctl] = *(const shortx8*)(Vt + (size_t)(256 + ctl * 16 + lr) * LV +
                                 cb0 + quad * 8);

  // ---- Softmax in-register.  Thread holds rows quad*4+r, cols {lr, lr+16}.
  {
    const float scale = 0.044194173824159216f;   // 512^-0.5
    floatx4 wv = *(const floatx4*)(width + pw + quad * 4);
#pragma unroll
    for (int r = 0; r < 4; ++r) {
      const int row = quad * 4 + r;
      const int d0  = lr - row;            // window slot of col lr
      const int d1  = d0 + 16;             // window slot of col lr+16
      const int jb0 = pibw + lr - 8;       // k position within batch
      const int jb1 = jb0 + 16;
      float rel0 = fabsf((float)(d0 - 8));
      float rel1 = fabsf((float)(d1 - 8));
      float mk0 = 1.f / (1.f + __expf(-5.f * (wv[r] - rel0)));
      float mk1 = 1.f / (1.f + __expf(-5.f * (wv[r] - rel1)));
      float val0 = (d0 >= 0)
          ? (((unsigned)jb0 < 8192u ? s0[r] * scale : 0.f) - (1.f - mk0) * 10000.f)
          : -1e30f;
      float val1 = (d1 <= 16)
          ? (((unsigned)jb1 < 8192u ? s1[r] * scale : 0.f) - (1.f - mk1) * 10000.f)
          : -1e30f;
      float mx = fmaxf(val0, val1);
#pragma unroll
      for (int m = 8; m >= 1; m >>= 1) mx = fmaxf(mx, __shfl_xor(mx, m, 64));
      float e0 = __expf(val0 - mx), e1 = __expf(val1 - mx);
      float sum = e0 + e1;
#pragma unroll
      for (int m = 8; m >= 1; m >>= 1) sum += __shfl_xor(sum, m, 64);
      const float inv = 1.f / sum;
      // +1 at the self slot (d==8) folds the "+ v Wout" into PV
      P[wave][row][lr]      = f2b(e0 * inv + (d0 == 8 ? 1.f : 0.f));
      P[wave][row][lr + 16] = f2b(e1 * inv + (d1 == 8 ? 1.f : 0.f));
    }
  }
  // P write->read is same-wave: DS ops are in-order per wave, no barrier.
  shortx8 pf = *(const shortx8*)&P[wave][lr][quad * 8];  // A[m=lr][k=quad*8+j]

  // ---- PV: out frag (row=pos quad*4+r, col=channel lr) -> direct fp32 store
#pragma unroll
  for (int ctl = 0; ctl < 16; ++ctl) {
    floatx4 o = __builtin_amdgcn_mfma_f32_16x16x32_bf16(pf, vfA[ctl],
                                                        (floatx4)0.0f, 0, 0, 0);
#pragma unroll
    for (int r = 0; r < 4; ++r)
      Out[(size_t)(pw + quad * 4 + r) * 512 + ctl * 16 + lr] = o[r];
  }
#pragma unroll
  for (int ctl = 0; ctl < 16; ++ctl) {
    floatx4 o = __builtin_amdgcn_mfma_f32_16x16x32_bf16(pf, vfB[ctl],
                                                        (floatx4)0.0f, 0, 0, 0);
#pragma unroll
    for (int r = 0; r < 4; ++r)
      Out[(size_t)(pw + quad * 4 + r) * 512 + 256 + ctl * 16 + lr] = o[r];
  }
}

// ---------------------------------------------------------------------------
extern "C" void kernel_launch(void* const* d_in, const int* in_sizes, int n_in,
                              void* d_out, int out_size, void* d_ws, size_t ws_size,
                              hipStream_t stream) {
  const float* x       = (const float*)d_in[0];  // [2,8192,512] fp32
  const float* w_qkv   = (const float*)d_in[1];  // [512,1536]  fp32
  const float* w_width = (const float*)d_in[2];  // [512,1]     fp32
  const float* b_width = (const float*)d_in[3];  // [1]         fp32
  const float* w_out   = (const float*)d_in[4];  // [512,512]   fp32
  float* out = (float*)d_out;                    // [2,8192,512] fp32

  const int M = 16384;
  char* ws = (char*)d_ws;
  // HBM-channel stagger (R6 win): consecutive large buffers offset by an
  // extra 8KB so no two hot read streams (Qm / xb / Vt) are 16MB-aligned.
  // [0,8192)           guard page (below-batch K-window reads land here)
  u16*   xb    = (u16*)(ws + 8192);                // 16,777,216
  u16*   Qb    = (u16*)(ws + 16793600);            // 16,777,216 (Qm)
  u16*   Vt    = (u16*)(ws + 33579008);            // 512*16416*2 = 16,809,984
  u16*   BtAll = (u16*)(ws + 50397184);            // McT | WvoT = 1,048,576
  u16*   woutT = (u16*)(ws + 51445760);            //    524,288
  float* width = (float*)(ws + 51970048);          //     65,536

  prep0<<<dim3(256), dim3(256), 0, stream>>>(w_out, woutT);
  prep<<<dim3(4192), dim3(256), 0, stream>>>(x, w_width, b_width, w_qkv,
                                             woutT, xb, width, BtAll, Vt);
  gemm_qv<<<dim3(M / 128, 8), dim3(256), 0, stream>>>(xb, BtAll, Qb, Vt);
  attn_fused<<<dim3(M / 64), dim3(256), 0, stream>>>(Qb, xb, Vt, width, out);
}

// Round 9
// 146.668 us; speedup vs baseline: 1.1249x; 1.0118x over previous
//
#include <hip/hip_runtime.h>

typedef unsigned short u16;
typedef unsigned int   u32;
typedef __attribute__((ext_vector_type(8))) short          shortx8;
typedef __attribute__((ext_vector_type(8))) unsigned short ushortx8;
typedef __attribute__((ext_vector_type(4))) float          floatx4;

#define AS1 __attribute__((address_space(1)))
#define AS3 __attribute__((address_space(3)))

#define SEG 8208   // 8192 + 16 pad cols per batch segment of Vt
#define LV  16416  // 2 * SEG

__device__ __forceinline__ float b2f(u16 v) {
  return __uint_as_float(((u32)v) << 16);
}
__device__ __forceinline__ u16 f2b(float f) {
  u32 u = __float_as_uint(f);
  u += 0x7FFF + ((u >> 16) & 1);   // RNE
  return (u16)(u >> 16);
}
__device__ __forceinline__ void cp16(const void* g, void* l) {
  // 16B/lane global->LDS DMA; LDS dest must be wave-uniform base + lane*16
  __builtin_amdgcn_global_load_lds((AS1 u32*)g, (AS3 u32*)l, 16, 0, 0);
}

// ---------------------------------------------------------------------------
// prep0: w_out (fp32, row-major [k][j]) -> woutT (bf16, [j][k]).  Runs before
// prep on the same stream, so prep's Wvo mini-GEMM can read B coalesced.
__global__ __launch_bounds__(256)
void prep0(const float* __restrict__ w_out, u16* __restrict__ woutT) {
  __shared__ u16 tile[32][33];
  const int t  = blockIdx.x;          // 256 = 16x16 tiles of 32x32
  const int cb = (t & 15) * 32;       // j block
  const int rb = (t >> 4) * 32;       // k block
  const int tx = threadIdx.x & 31;
  const int ty = threadIdx.x >> 5;
#pragma unroll
  for (int i = 0; i < 32; i += 8)
    tile[ty + i][tx] = f2b(w_out[(size_t)(rb + ty + i) * 512 + cb + tx]);
  __syncthreads();
#pragma unroll
  for (int i = 0; i < 32; i += 8)
    woutT[(size_t)(cb + ty + i) * 512 + rb + tx] = tile[tx][ty + i];
}

// ---------------------------------------------------------------------------
// Fused prep.  Block map (mini-GEMMs FIRST so they run under the casts):
//   [0,16)        Mc  = Wq @ Wk^T  -> BtAll rows    0-511  (=McT)
//   [16,32)       Wvo = Wv @ Wout  -> BtAll rows 512-1023  (=WvoT)
//                 (scores = x Mc x^T replaces Q.K^T; Vw = x Wvo makes the
//                  attention PV output THE final output -- proj deleted)
//   [32,4128)     cast x->bf16 (to guarded xb) + width rows
//   [4128,4192)   Vt pad-column zeroing
__global__ __launch_bounds__(256)
void prep(const float* __restrict__ x, const float* __restrict__ w_width,
          const float* __restrict__ b_width, const float* __restrict__ w_qkv,
          const u16* __restrict__ woutT, u16* __restrict__ xb,
          float* __restrict__ width, u16* __restrict__ BtAll,
          u16* __restrict__ Vt) {
  __shared__ alignas(16) u16 shb[17408];   // mini-GEMM staging / epilogue
  const int b = blockIdx.x;
  if (b < 32) {                      // ---- Mc / Wvo mini-GEMM (128x128 tile)
    const bool isMc = (b < 16);
    const int t    = isMc ? b : b - 16;
    const int row0 = (t >> 2) * 128;       // A-row (i) block
    const int col0 = (t & 3) * 128;        // out-col (j) block
    const int tid  = threadIdx.x;
    const int lane = tid & 63;
    const int wave = tid >> 6;
    const int quad = lane >> 4;
    const int lr   = lane & 15;
    const int wr   = (wave >> 1) * 64;
    const int wc   = (wave & 1) * 64;
    u16* As = shb;
    u16* Bs = shb + 8192;

    floatx4 acc[4][4];
#pragma unroll
    for (int i = 0; i < 4; ++i)
#pragma unroll
      for (int j = 0; j < 4; ++j) acc[i][j] = (floatx4)0.0f;

    int srow[4], scol[4];
#pragma unroll
    for (int p = 0; p < 4; ++p) {
      int c = p * 256 + tid;
      srow[p] = c >> 3;
      scol[p] = ((c & 7) ^ (srow[p] & 7)) * 8;
    }
    const int swz = lr & 7;

    for (int k0 = 0; k0 < 512; k0 += 64) {
      // A: Mc -> Wq rows; Wvo -> Wv rows (w_qkv cols 1024+k).  Coalesced.
#pragma unroll
      for (int p = 0; p < 4; ++p) {
        const float* ga = w_qkv + (size_t)(row0 + srow[p]) * 1536 +
                          (isMc ? 0 : 1024) + k0 + scol[p];
        floatx4 a0 = *(const floatx4*)ga;
        floatx4 a1 = *(const floatx4*)(ga + 4);
        ushortx8 o;
#pragma unroll
        for (int j = 0; j < 4; ++j) { o[j] = f2b(a0[j]); o[4 + j] = f2b(a1[j]); }
        *(ushortx8*)&As[(p * 256 + tid) * 8] = o;
      }
      // B: Mc -> Wk rows (w_qkv cols 512+k, fp32); Wvo -> woutT rows (bf16).
#pragma unroll
      for (int p = 0; p < 4; ++p) {
        ushortx8 o;
        if (isMc) {
          const float* gb = w_qkv + (size_t)(col0 + srow[p]) * 1536 + 512 +
                            k0 + scol[p];
          floatx4 b0 = *(const floatx4*)gb;
          floatx4 b1 = *(const floatx4*)(gb + 4);
#pragma unroll
          for (int j = 0; j < 4; ++j) { o[j] = f2b(b0[j]); o[4 + j] = f2b(b1[j]); }
        } else {
          o = *(const ushortx8*)(woutT + (size_t)(col0 + srow[p]) * 512 +
                                 k0 + scol[p]);
        }
        *(ushortx8*)&Bs[(p * 256 + tid) * 8] = o;
      }
      __syncthreads();
#pragma unroll
      for (int ks = 0; ks < 2; ++ks) {
        shortx8 af[4], bf[4];
#pragma unroll
        for (int mi = 0; mi < 4; ++mi)
          af[mi] = *(const shortx8*)
              &As[((wr + mi * 16 + lr) * 8 + ((ks * 4 + quad) ^ swz)) * 8];
#pragma unroll
        for (int ni = 0; ni < 4; ++ni)
          bf[ni] = *(const shortx8*)
              &Bs[((wc + ni * 16 + lr) * 8 + ((ks * 4 + quad) ^ swz)) * 8];
#pragma unroll
        for (int mi = 0; mi < 4; ++mi)
#pragma unroll
          for (int ni = 0; ni < 4; ++ni)
            acc[mi][ni] = __builtin_amdgcn_mfma_f32_16x16x32_bf16(
                af[mi], bf[ni], acc[mi][ni], 0, 0, 0);
      }
      __syncthreads();
    }
    // transposed epilogue: BtAll[(Wvo? +512) + col0+j][row0+i]
    u16* outp = BtAll + (isMc ? 0 : (size_t)512 * 512);
#pragma unroll
    for (int mi = 0; mi < 4; ++mi)
#pragma unroll
      for (int ni = 0; ni < 4; ++ni)
#pragma unroll
        for (int r = 0; r < 4; ++r)
          shb[(wc + ni * 16 + lr) * 136 + wr + mi * 16 + quad * 4 + r] =
              f2b(acc[mi][ni][r]);
    __syncthreads();
    const int rr = tid >> 4, cc = (tid & 15) * 8;
#pragma unroll
    for (int it = 0; it < 8; ++it) {
      int chl = it * 16 + rr;
      *(ushortx8*)(outp + (size_t)(col0 + chl) * 512 + row0 + cc) =
          *(const ushortx8*)&shb[chl * 136 + cc];
    }
  } else if (b < 4128) {             // ---- cast x -> bf16, compute width
    const int lane = threadIdx.x & 63;
    const int row  = (b - 32) * 4 + (threadIdx.x >> 6);
    const float* xp = x + (size_t)row * 512 + lane * 8;
    floatx4 v0 = *(const floatx4*)xp;
    floatx4 v1 = *(const floatx4*)(xp + 4);
    floatx4 w0 = *(const floatx4*)(w_width + lane * 8);
    floatx4 w1 = *(const floatx4*)(w_width + lane * 8 + 4);
    float s = 0.f;
    ushortx8 o;
#pragma unroll
    for (int j = 0; j < 4; ++j) {
      s += v0[j] * w0[j] + v1[j] * w1[j];
      o[j] = f2b(v0[j]); o[4 + j] = f2b(v1[j]);
    }
    *(ushortx8*)(xb + (size_t)row * 512 + lane * 8) = o;
#pragma unroll
    for (int m = 32; m >= 1; m >>= 1) s += __shfl_xor(s, m, 64);
    if (lane == 0)
      width[row] = 16.f / (1.f + __expf(-(s + b_width[0]))) + 1.f;
  } else {                           // ---- Vt pad-column zeroing
    const int idx = (b - 4128) * 256 + threadIdx.x;  // 512 ch * 32 pad cols
    const int ch = idx >> 5;
    const int k  = idx & 31;
    const int seg = k >> 4;
    const int j   = k & 15;
    const int col = seg * SEG + (j < 8 ? j : 8192 + j);
    Vt[(size_t)ch * LV + col] = 0;
  }
}

// ---------------------------------------------------------------------------
// C = A[M][512] @ Bt[N][512]^T, bf16 in, fp32 acc.  128x128 tile, BK=64,
// XOR-swizzled LDS staging, LDS-shuffled coalesced epilogues.  N=1024:
// cols [0,512) -> Qm rows (Qb); cols [512,1024) -> Vw, transposed scatter
// into batch-padded Vt (Vw = x @ (Wv Wout): PV output is the FINAL output).
//
// XCD-chunked block swizzle (T1): HW round-robins wgid%8 -> XCD.  logical =
// (wgid&7)*128 + wgid>>3 gives each XCD a contiguous span of 16 row-tiles,
// walked col-fastest (col0 = (logical&7)*128), so the 8 blocks sharing an
// A-tile run back-to-back on ONE XCD (A-tile 128KB L2-hot) and the whole B
// (1MB) is L2-resident per XCD.  Old 2D grid refetched A ~8x from HBM
// (134MB); now ~17MB + 8MB B.
__global__ __launch_bounds__(256, 3)
void gemm_qv(const u16* __restrict__ A, const u16* __restrict__ Bt,
             u16* __restrict__ Qb, u16* __restrict__ Vt) {
  const int K = 512;
  __shared__ alignas(16) u16 lds[17408];        // 34,816 B (union)
  u16* As = lds;                                // 8192 u16 (128 x 64)
  u16* Bs = lds + 8192;                         // 8192 u16
  const int tid  = threadIdx.x;
  const int lane = tid & 63;
  const int wave = tid >> 6;
  const int quad = lane >> 4;
  const int lr   = lane & 15;
  const int logical = (blockIdx.x & 7) * 128 + (blockIdx.x >> 3);
  const int row0 = (logical >> 3) * 128;
  const int col0 = (logical & 7) * 128;
  const int wr   = (wave >> 1) * 64;
  const int wc   = (wave & 1) * 64;

  floatx4 acc[4][4];
#pragma unroll
  for (int i = 0; i < 4; ++i)
#pragma unroll
    for (int j = 0; j < 4; ++j) acc[i][j] = (floatx4)0.0f;

  // chunk c = p*256+tid -> LDS slot c; row c>>3, phys colblk (c&7)^(row&7)
  int srow[4], scol[4];
#pragma unroll
  for (int p = 0; p < 4; ++p) {
    int c = p * 256 + tid;
    srow[p] = c >> 3;
    scol[p] = ((c & 7) ^ (srow[p] & 7)) * 8;
  }
  const int swz = lr & 7;

  for (int k0 = 0; k0 < K; k0 += 64) {
#pragma unroll
    for (int p = 0; p < 4; ++p)
      cp16(A + (size_t)(row0 + srow[p]) * K + k0 + scol[p], &As[(p * 256 + tid) * 8]);
#pragma unroll
    for (int p = 0; p < 4; ++p)
      cp16(Bt + (size_t)(col0 + srow[p]) * K + k0 + scol[p], &Bs[(p * 256 + tid) * 8]);
    __syncthreads();

#pragma unroll
    for (int ks = 0; ks < 2; ++ks) {
      shortx8 af[4], bf[4];
#pragma unroll
      for (int mi = 0; mi < 4; ++mi)
        af[mi] = *(const shortx8*)
            &As[((wr + mi * 16 + lr) * 8 + ((ks * 4 + quad) ^ swz)) * 8];
#pragma unroll
      for (int ni = 0; ni < 4; ++ni)
        bf[ni] = *(const shortx8*)
            &Bs[((wc + ni * 16 + lr) * 8 + ((ks * 4 + quad) ^ swz)) * 8];
#pragma unroll
      for (int mi = 0; mi < 4; ++mi)
#pragma unroll
        for (int ni = 0; ni < 4; ++ni)
          acc[mi][ni] = __builtin_amdgcn_mfma_f32_16x16x32_bf16(
              af[mi], bf[ni], acc[mi][ni], 0, 0, 0);
    }
    __syncthreads();
  }

  // C/D layout: col = lane&15, row = quad*4 + reg  [verified m89/m91]
  if (col0 < 512) {                  // ---- Qm: row-major LDS, coalesced out
    const int cb = col0;
#pragma unroll
    for (int mi = 0; mi < 4; ++mi)
#pragma unroll
      for (int ni = 0; ni < 4; ++ni)
#pragma unroll
        for (int r = 0; r < 4; ++r)
          lds[(wr + mi * 16 + quad * 4 + r) * 136 + wc + ni * 16 + lr] =
              f2b(acc[mi][ni][r]);
    __syncthreads();
    const int rr = tid >> 4, cc = (tid & 15) * 8;
#pragma unroll
    for (int it = 0; it < 8; ++it) {
      int row = it * 16 + rr;
      *(ushortx8*)(Qb + (size_t)(row0 + row) * 512 + cb + cc) =
          *(const ushortx8*)&lds[row * 136 + cc];
    }
  } else {                           // ---- Vw: transposed LDS, coalesced out
    const int cb = col0 - 512;
    const int bb = row0 >> 13, pib0 = row0 & 8191;
#pragma unroll
    for (int mi = 0; mi < 4; ++mi)
#pragma unroll
      for (int ni = 0; ni < 4; ++ni)
#pragma unroll
        for (int r = 0; r < 4; ++r)
          lds[(wc + ni * 16 + lr) * 136 + wr + mi * 16 + quad * 4 + r] =
              f2b(acc[mi][ni][r]);
    __syncthreads();
    const int rr = tid >> 4, cc = (tid & 15) * 8;
#pragma unroll
    for (int it = 0; it < 8; ++it) {
      int chl = it * 16 + rr;
      ushortx8 v = *(const ushortx8*)&lds[chl * 136 + cc];
      *(ushortx8*)(Vt + (size_t)(cb + chl) * LV + (size_t)bb * SEG + 8 + pib0 + cc) = v;
    }
  }
}

// ---------------------------------------------------------------------------
// Fused local attention, v5: PV output IS the final output (Vw = x WvWout),
// so there is no projection phase, no Osw round-trip, and NO barriers --
// each wave owns 16 rows end-to-end: QK^T (Qm.x), in-reg softmax, PV -> fp32
// stores.  "+v Wout" residual = Vw[self], folded via P's +1 self slot.
// XCD-chunked swizzle: neighbor blocks share ~20% of the Kx window; keeping
// a contiguous 2048-position span per XCD turns that overlap into L2 hits.
__global__ __launch_bounds__(256, 1)
void attn_fused(const u16* __restrict__ Q, const u16* __restrict__ Kx,
                const u16* __restrict__ Vt, const float* __restrict__ width,
                float* __restrict__ Out) {
  __shared__ alignas(16) u16 P[4][16][32];    // 4KB: per-wave P (A-layout)
  const int tid  = threadIdx.x;
  const int lane = tid & 63;
  const int wave = tid >> 6;
  const int quad = lane >> 4;
  const int lr   = lane & 15;
  const int p0   = ((blockIdx.x & 7) * 32 + (blockIdx.x >> 3)) * 64;
  const int pw   = p0 + wave * 16;
  const int pibw = pw & 8191;
  const int bb   = pw >> 13;
  const size_t cb0 = (size_t)bb * SEG + pibw;   // Vt col of window slot 0

  // ---- hoisted Vw half-0 loads (independent of all other phases)
  shortx8 vfA[16];
#pragma unroll
  for (int ctl = 0; ctl < 16; ++ctl)
    vfA[ctl] = *(const shortx8*)(Vt + (size_t)(ctl * 16 + lr) * LV +
                                 cb0 + quad * 8);

  // ---- Phase A: scores 16x32 over all 512 channels (this wave's rows)
  floatx4 s0 = (floatx4)0.0f, s1 = (floatx4)0.0f;
#pragma unroll 4
  for (int s = 0; s < 16; ++s) {
    const int k0 = s * 32 + quad * 8;
    shortx8 af = *(const shortx8*)(Q  + (size_t)(pw + lr) * 512 + k0);
    shortx8 f0 = *(const shortx8*)(Kx + (ptrdiff_t)(pw - 8 + lr) * 512 + k0);
    shortx8 f1 = *(const shortx8*)(Kx + (ptrdiff_t)(pw + 8 + lr) * 512 + k0);
    s0 = __builtin_amdgcn_mfma_f32_16x16x32_bf16(af, f0, s0, 0, 0, 0);
    s1 = __builtin_amdgcn_mfma_f32_16x16x32_bf16(af, f1, s1, 0, 0, 0);
  }

  // ---- issue Vw half-1 loads; they land during softmax / PV(h0)
  shortx8 vfB[16];
#pragma unroll
  for (int ctl = 0; ctl < 16; ++ctl)
    vfB[ctl] = *(const shortx8*)(Vt + (size_t)(256 + ctl * 16 + lr) * LV +
                                 cb0 + quad * 8);

  // ---- Softmax in-register.  Thread holds rows quad*4+r, cols {lr, lr+16}.
  {
    const float scale = 0.044194173824159216f;   // 512^-0.5
    floatx4 wv = *(const floatx4*)(width + pw + quad * 4);
#pragma unroll
    for (int r = 0; r < 4; ++r) {
      const int row = quad * 4 + r;
      const int d0  = lr - row;            // window slot of col lr
      const int d1  = d0 + 16;             // window slot of col lr+16
      const int jb0 = pibw + lr - 8;       // k position within batch
      const int jb1 = jb0 + 16;
      float rel0 = fabsf((float)(d0 - 8));
      float rel1 = fabsf((float)(d1 - 8));
      float mk0 = 1.f / (1.f + __expf(-5.f * (wv[r] - rel0)));
      float mk1 = 1.f / (1.f + __expf(-5.f * (wv[r] - rel1)));
      float val0 = (d0 >= 0)
          ? (((unsigned)jb0 < 8192u ? s0[r] * scale : 0.f) - (1.f - mk0) * 10000.f)
          : -1e30f;
      float val1 = (d1 <= 16)
          ? (((unsigned)jb1 < 8192u ? s1[r] * scale : 0.f) - (1.f - mk1) * 10000.f)
          : -1e30f;
      float mx = fmaxf(val0, val1);
#pragma unroll
      for (int m = 8; m >= 1; m >>= 1) mx = fmaxf(mx, __shfl_xor(mx, m, 64));
      float e0 = __expf(val0 - mx), e1 = __expf(val1 - mx);
      float sum = e0 + e1;
#pragma unroll
      for (int m = 8; m >= 1; m >>= 1) sum += __shfl_xor(sum, m, 64);
      const float inv = 1.f / sum;
      // +1 at the self slot (d==8) folds the "+ v Wout" into PV
      P[wave][row][lr]      = f2b(e0 * inv + (d0 == 8 ? 1.f : 0.f));
      P[wave][row][lr + 16] = f2b(e1 * inv + (d1 == 8 ? 1.f : 0.f));
    }
  }
  // P write->read is same-wave: DS ops are in-order per wave, no barrier.
  shortx8 pf = *(const shortx8*)&P[wave][lr][quad * 8];  // A[m=lr][k=quad*8+j]

  // ---- PV: out frag (row=pos quad*4+r, col=channel lr) -> direct fp32 store
#pragma unroll
  for (int ctl = 0; ctl < 16; ++ctl) {
    floatx4 o = __builtin_amdgcn_mfma_f32_16x16x32_bf16(pf, vfA[ctl],
                                                        (floatx4)0.0f, 0, 0, 0);
#pragma unroll
    for (int r = 0; r < 4; ++r)
      Out[(size_t)(pw + quad * 4 + r) * 512 + ctl * 16 + lr] = o[r];
  }
#pragma unroll
  for (int ctl = 0; ctl < 16; ++ctl) {
    floatx4 o = __builtin_amdgcn_mfma_f32_16x16x32_bf16(pf, vfB[ctl],
                                                        (floatx4)0.0f, 0, 0, 0);
#pragma unroll
    for (int r = 0; r < 4; ++r)
      Out[(size_t)(pw + quad * 4 + r) * 512 + 256 + ctl * 16 + lr] = o[r];
  }
}

// ---------------------------------------------------------------------------
extern "C" void kernel_launch(void* const* d_in, const int* in_sizes, int n_in,
                              void* d_out, int out_size, void* d_ws, size_t ws_size,
                              hipStream_t stream) {
  const float* x       = (const float*)d_in[0];  // [2,8192,512] fp32
  const float* w_qkv   = (const float*)d_in[1];  // [512,1536]  fp32
  const float* w_width = (const float*)d_in[2];  // [512,1]     fp32
  const float* b_width = (const float*)d_in[3];  // [1]         fp32
  const float* w_out   = (const float*)d_in[4];  // [512,512]   fp32
  float* out = (float*)d_out;                    // [2,8192,512] fp32

  const int M = 16384;
  char* ws = (char*)d_ws;
  // HBM-channel stagger (R6 win): consecutive large buffers offset by an
  // extra 8KB so no two hot read streams (Qm / xb / Vt) are 16MB-aligned.
  // [0,8192)           guard page (below-batch K-window reads land here)
  u16*   xb    = (u16*)(ws + 8192);                // 16,777,216
  u16*   Qb    = (u16*)(ws + 16793600);            // 16,777,216 (Qm)
  u16*   Vt    = (u16*)(ws + 33579008);            // 512*16416*2 = 16,809,984
  u16*   BtAll = (u16*)(ws + 50397184);            // McT | WvoT = 1,048,576
  u16*   woutT = (u16*)(ws + 51445760);            //    524,288
  float* width = (float*)(ws + 51970048);          //     65,536

  prep0<<<dim3(256), dim3(256), 0, stream>>>(w_out, woutT);
  prep<<<dim3(4192), dim3(256), 0, stream>>>(x, w_width, b_width, w_qkv,
                                             woutT, xb, width, BtAll, Vt);
  gemm_qv<<<dim3(1024), dim3(256), 0, stream>>>(xb, BtAll, Qb, Vt);
  attn_fused<<<dim3(M / 64), dim3(256), 0, stream>>>(Qb, xb, Vt, width, out);
}